// Round 13
// baseline (4053.297 us; speedup 1.0000x reference)
//
#include <hip/hip_runtime.h>
#include <hip/hip_bf16.h>
#include <hip/hip_cooperative_groups.h>
#include <cstddef>

namespace cg = cooperative_groups;

typedef short bf16x8 __attribute__((ext_vector_type(8)));
typedef float f32x4 __attribute__((ext_vector_type(4)));

// Constants for this problem: V=4096, D=1024, H=1024, B=64, T=512

__device__ __forceinline__ short bf16rne(float f) {
  unsigned u = __builtin_bit_cast(unsigned, f);
  u += 0x7fffu + ((u >> 16) & 1u);
  return (short)(u >> 16);
}

// Inline tanh (no ocml call: a call forces caller-saved spills of wfrag).
__device__ __forceinline__ float fast_tanh(float x) {
  float e = __builtin_amdgcn_exp2f(x * 2.88539008177792681f);
  return 1.0f - 2.0f * __builtin_amdgcn_rcpf(e + 1.0f);
}

// L1-bypassing load of the LOCAL L2 (sc0 only); waitcnt inside the asm.
__device__ __forceinline__ unsigned load_l2(const unsigned int* p) {
  unsigned v;
  asm volatile("global_load_dword %0, %1, off sc0\n\ts_waitcnt vmcnt(0)"
               : "=v"(v) : "v"(p) : "memory");
  return v;
}

// Raw L2-resident atomic add (no sc bits -> executes in the issuing XCD's L2).
__device__ __forceinline__ void atom_add_l2(unsigned int* p, unsigned v) {
  asm volatile("global_atomic_add %0, %1, off" :: "v"(p), "v"(v) : "memory");
}

// ---------------- K0a: elementwise f32 -> bf16 convert (x4 per thread) ----------------
__global__ void conv_f32_bf16_x4(const float* __restrict__ src, short* __restrict__ dst, int n4) {
  int i = blockIdx.x * blockDim.x + threadIdx.x;
  if (i >= n4) return;
  float4 v = ((const float4*)src)[i];
  unsigned long long o =
      (unsigned long long)(unsigned short)bf16rne(v.x) |
      ((unsigned long long)(unsigned short)bf16rne(v.y) << 16) |
      ((unsigned long long)(unsigned short)bf16rne(v.z) << 32) |
      ((unsigned long long)(unsigned short)bf16rne(v.w) << 48);
  ((unsigned long long*)dst)[i] = o;
}

// ---------------- K0b: tiled transpose + convert: dst[c][r] = bf16(src[r][c]) ----------------
__global__ void transpose_conv(const float* __restrict__ src, short* __restrict__ dst,
                               int R, int C) {
  __shared__ float tile[32][33];
  int tx = threadIdx.x, ty = threadIdx.y;
  int bx = blockIdx.x, by = blockIdx.y;
#pragma unroll
  for (int i = 0; i < 4; ++i)
    tile[ty + i * 8][tx] = src[(size_t)(by * 32 + ty + i * 8) * C + bx * 32 + tx];
  __syncthreads();
#pragma unroll
  for (int i = 0; i < 4; ++i)
    dst[(size_t)(bx * 32 + ty + i * 8) * R + by * 32 + tx] = bf16rne(tile[tx][ty + i * 8]);
}

// ---------------- K1/K3: 128x128 tile MFMA GEMM, BK=32, 4 waves (2x2 of 64x64) ----------------
template <bool GATHER, bool OUT_BF16>
__global__ __launch_bounds__(256) void gemm_bf16(
    const short* __restrict__ Abase, const int* __restrict__ gidx,
    const short* __restrict__ BT, const float* __restrict__ bias,
    void* __restrict__ Cout, int M, int N, int K) {
  __shared__ short As[128][40];
  __shared__ short Bs[128][40];
  const int tid = threadIdx.x;
  const int lane = tid & 63;
  const int wave = tid >> 6;
  const int mbase = blockIdx.x * 128;
  const int nbase = blockIdx.y * 128;
  const int wr = (wave >> 1) * 64;
  const int wc = (wave & 1) * 64;
  const int l15 = lane & 15;
  const int lk8 = (lane >> 4) * 8;
  const int r0 = tid >> 2;
  const int kc = (tid & 3) * 8;

  f32x4 acc[4][4] = {};

  for (int k0 = 0; k0 < K; k0 += 32) {
#pragma unroll
    for (int h = 0; h < 2; ++h) {
      int r = r0 + h * 64;
      size_t arow;
      if (GATHER) arow = (size_t)gidx[mbase + r];
      else        arow = (size_t)(mbase + r);
      *(bf16x8*)&As[r][kc] = *(const bf16x8*)(Abase + arow * (size_t)K + k0 + kc);
      *(bf16x8*)&Bs[r][kc] = *(const bf16x8*)(BT + (size_t)(nbase + r) * K + k0 + kc);
    }
    __syncthreads();
    bf16x8 af[4], bfr[4];
#pragma unroll
    for (int i = 0; i < 4; ++i) {
      af[i]  = *(const bf16x8*)&As[wr + i * 16 + l15][lk8];
      bfr[i] = *(const bf16x8*)&Bs[wc + i * 16 + l15][lk8];
    }
#pragma unroll
    for (int i = 0; i < 4; ++i)
#pragma unroll
      for (int j = 0; j < 4; ++j)
        acc[i][j] = __builtin_amdgcn_mfma_f32_16x16x32_bf16(af[i], bfr[j], acc[i][j], 0, 0, 0);
    __syncthreads();
  }

#pragma unroll
  for (int i = 0; i < 4; ++i)
#pragma unroll
    for (int j = 0; j < 4; ++j) {
      int col = nbase + wc + j * 16 + l15;
      float bv = bias ? bias[col] : 0.f;
#pragma unroll
      for (int r = 0; r < 4; ++r) {
        int row = mbase + wr + i * 16 + (lane >> 4) * 4 + r;
        float v = acc[i][j][r] + bv;
        if (OUT_BF16) ((short*)Cout)[(size_t)row * N + col] = bf16rne(v);
        else          ((float*)Cout)[(size_t)row * N + col] = v;
      }
    }
}

// ---------------- K2: recurrence, XCD-local data path with verified probe ----------------
// 128 blocks x 256 threads. Domain d = bid&7 (16 blocks, members bid = d+8m;
// same XCD under round-robin) owns batches [d*8, d*8+8); member m owns cols
// [m*64, m*64+64). Transposed MFMA: z^T = mfma(A=WrT, B=h^T); lanes l15<8
// store one packed 8B (batch d*8+l15, 4 consecutive cols).
//
// PROBE (once): publish HW_REG_XCC_ID device-scope, cg grid.sync (runtime's
// own barrier), check domain uniformity -> fast.
// DATA: fast -> PLAIN writeback stores (vmcnt retires at LOCAL L2 — no IF ack
// on the critical path; same-XCD consumers read the dirty L2 lines; K3 sees
// them via the end-of-dispatch L2 flush, same mechanism as K1->K2's xp).
// !fast -> R12's sc1 write-through (placement-independent).
// FLAG (hang-proof either way): wave0-lane0 bumps cntL (raw local-L2 atomic),
// wave3-lane0 bumps cntG (device scope at IF). Poller releases on EITHER.
__global__ __launch_bounds__(256, 1) void rnn_recur(
    const float* __restrict__ xp, const short* __restrict__ WrT,
    const float* __restrict__ h0, short* __restrict__ hs,
    unsigned int* __restrict__ bar) {
  const int tid = threadIdx.x;
  const int lane = tid & 63;
  const int wave = tid >> 6;
  const int bid = blockIdx.x;           // 0..127
  const int d = bid & 7;                // domain (== XCD under round-robin)
  const int m = bid >> 3;               // col-slice 0..15
  const int rowbase = d * 8;
  const int colbase = m * 64 + wave * 16;
  const int l15 = lane & 15;
  const int lk8 = (lane >> 4) * 8;
  unsigned int* cntL = bar + d * 32;          // local-L2 counter
  unsigned int* cntG = bar + 512 + d * 32;    // IF ground-truth counter
  unsigned int* xcc  = bar + 896;             // [128] probe results

  // ---- placement probe (before wfrag preload: grid.sync is a call) ----
  unsigned myx = 0;
  asm volatile("s_getreg_b32 %0, hwreg(HW_REG_XCC_ID)" : "=s"(myx));
  if (tid == 0)
    __hip_atomic_store(&xcc[bid], myx + 1u, __ATOMIC_RELAXED, __HIP_MEMORY_SCOPE_AGENT);
  cg::this_grid().sync();
  bool fast = true;
  {
    unsigned x0 = __hip_atomic_load(&xcc[d], __ATOMIC_RELAXED, __HIP_MEMORY_SCOPE_AGENT);
    for (int mm = 1; mm < 16; ++mm)
      fast &= (__hip_atomic_load(&xcc[d + 8 * mm], __ATOMIC_RELAXED,
                                 __HIP_MEMORY_SCOPE_AGENT) == x0);
  }

  // A-operand: WrT rows = this wave's 16 output cols. Volatile: cannot remat.
  const int acol = colbase + l15;
  bf16x8 wfrag[32];
#pragma unroll
  for (int ks = 0; ks < 32; ++ks)
    wfrag[ks] = *(const volatile bf16x8*)(WrT + (size_t)acol * 1024 + ks * 32 + lk8);

  // Output mapping (transposed D): batch = lane&15 (only 8 valid), 4 cols.
  const int bl = rowbase + (l15 & 7);   // batch whose h-row this lane loads
  const int oc = colbase + (lane >> 4) * 4;
  const bool do_store = (l15 < 8);

  // ---- t = 0: previous h is h0 (broadcast row) ----
  {
    f32x4 a0 = {}, a1 = {}, a2 = {}, a3 = {};
#pragma unroll
    for (int ks = 0; ks < 32; ks += 4) {
      bf16x8 a[4];
#pragma unroll
      for (int q = 0; q < 4; ++q) {
        const float* hp = h0 + (ks + q) * 32 + lk8;
#pragma unroll
        for (int jj = 0; jj < 8; ++jj) a[q][jj] = bf16rne(hp[jj]);
      }
      a0 = __builtin_amdgcn_mfma_f32_16x16x32_bf16(wfrag[ks + 0], a[0], a0, 0, 0, 0);
      a1 = __builtin_amdgcn_mfma_f32_16x16x32_bf16(wfrag[ks + 1], a[1], a1, 0, 0, 0);
      a2 = __builtin_amdgcn_mfma_f32_16x16x32_bf16(wfrag[ks + 2], a[2], a2, 0, 0, 0);
      a3 = __builtin_amdgcn_mfma_f32_16x16x32_bf16(wfrag[ks + 3], a[3], a3, 0, 0, 0);
    }
    f32x4 acc = (a0 + a1) + (a2 + a3);
    if (do_store) {
      float4 x4 = *(const float4*)(xp + ((size_t)bl * 512 + 0) * 1024 + oc);
      unsigned long long p =
          (unsigned long long)(unsigned short)bf16rne(fast_tanh(acc[0] + x4.x)) |
          ((unsigned long long)(unsigned short)bf16rne(fast_tanh(acc[1] + x4.y)) << 16) |
          ((unsigned long long)(unsigned short)bf16rne(fast_tanh(acc[2] + x4.z)) << 32) |
          ((unsigned long long)(unsigned short)bf16rne(fast_tanh(acc[3] + x4.w)) << 48);
      unsigned long long* dp = (unsigned long long*)(hs + ((size_t)bl * 512 + 0) * 1024 + oc);
      if (fast) *dp = p;
      else __hip_atomic_store(dp, p, __ATOMIC_RELAXED, __HIP_MEMORY_SCOPE_AGENT);
    }
  }

  // prefetch xp for t = 1
  float4 xv = {0.f, 0.f, 0.f, 0.f};
  if (do_store)
    xv = *(const float4*)(xp + ((size_t)bl * 512 + 1) * 1024 + oc);

  for (int t = 1; t < 512; ++t) {
    // release: drain own h-stores (local-L2 ack if fast, IF ack if sc1),
    // block barrier, then split dual arrival (wave0: cntL, wave3: cntG so
    // the poller's vmcnt(0) never waits the IF atomic's ack).
    asm volatile("s_waitcnt vmcnt(0)" ::: "memory");
    __builtin_amdgcn_s_barrier();
    if (lane == 0) {
      if (wave == 0) atom_add_l2(cntL, 1u);       // local XCD L2
      else if (wave == 3) atomicAdd(cntG, 1u);    // IF ground truth
    }

    // prefetch xp for t+1 NOW — completes while we wait for peers
    const int tn = (t + 1 < 512) ? (t + 1) : 511;
    float4 xn = {0.f, 0.f, 0.f, 0.f};
    if (do_store)
      xn = *(const float4*)(xp + ((size_t)bl * 512 + tn) * 1024 + oc);

    // acquire: wave0 polls cntL fast (8x) with cntG as guaranteed fallback
    if (wave == 0) {
      const unsigned target = 16u * (unsigned)t;   // 16 blocks per domain
      for (;;) {
        bool ok = false;
#pragma unroll 1
        for (int k = 0; k < 8; ++k) {
          if (load_l2(cntL) >= target) { ok = true; break; }
          __builtin_amdgcn_s_sleep(1);
        }
        if (ok) break;
        if (__hip_atomic_load(cntG, __ATOMIC_RELAXED, __HIP_MEMORY_SCOPE_AGENT) >= target)
          break;
      }
    }
    __builtin_amdgcn_s_barrier();
    asm volatile("" ::: "memory");        // no static hoist of h loads above
    __builtin_amdgcn_sched_barrier(0);    // rule 18: pin ordering

    // B = h_{t-1}^T (batch bl): fresh addresses -> local-L2 dirty-line hit
    // (fast) or IF (slow). 4 independent accumulator chains.
    f32x4 a0 = {}, a1 = {}, a2 = {}, a3 = {};
    const short* hrow = hs + ((size_t)bl * 512 + (t - 1)) * 1024 + lk8;
#pragma unroll
    for (int ks = 0; ks < 32; ks += 4) {
      bf16x8 a[4];
#pragma unroll
      for (int q = 0; q < 4; ++q)
        a[q] = *(const bf16x8*)(hrow + (ks + q) * 32);
      a0 = __builtin_amdgcn_mfma_f32_16x16x32_bf16(wfrag[ks + 0], a[0], a0, 0, 0, 0);
      a1 = __builtin_amdgcn_mfma_f32_16x16x32_bf16(wfrag[ks + 1], a[1], a1, 0, 0, 0);
      a2 = __builtin_amdgcn_mfma_f32_16x16x32_bf16(wfrag[ks + 2], a[2], a2, 0, 0, 0);
      a3 = __builtin_amdgcn_mfma_f32_16x16x32_bf16(wfrag[ks + 3], a[3], a3, 0, 0, 0);
    }
    f32x4 acc = (a0 + a1) + (a2 + a3);

    if (do_store) {
      unsigned long long p =
          (unsigned long long)(unsigned short)bf16rne(fast_tanh(acc[0] + xv.x)) |
          ((unsigned long long)(unsigned short)bf16rne(fast_tanh(acc[1] + xv.y)) << 16) |
          ((unsigned long long)(unsigned short)bf16rne(fast_tanh(acc[2] + xv.z)) << 32) |
          ((unsigned long long)(unsigned short)bf16rne(fast_tanh(acc[3] + xv.w)) << 48);
      unsigned long long* dp = (unsigned long long*)(hs + ((size_t)bl * 512 + t) * 1024 + oc);
      if (fast) *dp = p;                  // writeback: ack at LOCAL L2
      else __hip_atomic_store(dp, p, __ATOMIC_RELAXED, __HIP_MEMORY_SCOPE_AGENT);
    }
    xv = xn;
  }
}

// ---------------- launch ----------------
extern "C" void kernel_launch(void* const* d_in, const int* in_sizes, int n_in,
                              void* d_out, int out_size, void* d_ws, size_t ws_size,
                              hipStream_t stream) {
  const int*   input = (const int*)d_in[0];    // [B][T] = [64][512]
  const float* embed = (const float*)d_in[1];  // [V][D] = [4096][1024]
  const float* Wc    = (const float*)d_in[2];  // [D+H][H] = [2048][1024]
  const float* bc    = (const float*)d_in[3];  // [H]
  const float* h0    = (const float*)d_in[4];  // [1][H]
  const float* Wh    = (const float*)d_in[5];  // [H][V] = [1024][4096]
  const float* bh    = (const float*)d_in[6];  // [V]

  char* ws = (char*)d_ws;
  float* xp   = (float*)(ws + 0);            // 32768*1024 f32  = 134,217,728 B
  short* hs   = (short*)(ws + 134217728);    // 32768*1024 bf16 =  67,108,864 B
  short* embB = (short*)(ws + 201326592);    // 4096*1024 bf16  =   8,388,608 B
  short* WxT  = (short*)(ws + 209715200);    // 1024*1024 bf16  =   2,097,152 B
  short* WrT  = (short*)(ws + 211812352);    // 1024*1024 bf16  =   2,097,152 B
  short* WhT  = (short*)(ws + 213909504);    // 4096*1024 bf16  =   8,388,608 B
  unsigned int* bar = (unsigned int*)(ws + 222298112);  // 4 KB counters

  hipMemsetAsync(bar, 0, 4096, stream);

  // K0: converts + transposes
  conv_f32_bf16_x4<<<4096, 256, 0, stream>>>(embed, embB, 1048576);
  transpose_conv<<<dim3(32, 32),  dim3(32, 8), 0, stream>>>(Wc,                WxT, 1024, 1024);
  transpose_conv<<<dim3(32, 32),  dim3(32, 8), 0, stream>>>(Wc + 1024 * 1024,  WrT, 1024, 1024);
  transpose_conv<<<dim3(128, 32), dim3(32, 8), 0, stream>>>(Wh,                WhT, 1024, 4096);

  // K1: xp = embed[input] @ Wx + bc   (f32 out)
  gemm_bf16<true, false><<<dim3(256, 8), 256, 0, stream>>>(
      embB, input, WxT, bc, (void*)xp, 32768, 1024, 1024);

  // K2: recurrence (cooperative launch: co-residency + grid.sync for probe)
  {
    const float* xp_c = xp;
    const short* WrT_c = WrT;
    const float* h0_c = h0;
    short* hs_c = hs;
    unsigned int* bar_c = bar;
    void* args[] = {(void*)&xp_c, (void*)&WrT_c, (void*)&h0_c, (void*)&hs_c, (void*)&bar_c};
    hipLaunchCooperativeKernel((const void*)rnn_recur, dim3(128), dim3(256), args, 0, stream);
  }

  // K3: out = hs @ Wh + bh  (f32 out)
  gemm_bf16<false, false><<<dim3(256, 32), 256, 0, stream>>>(
      hs, nullptr, WhT, bh, d_out, 32768, 4096, 1024);
}

// Round 14
// 3477.822 us; speedup vs baseline: 1.1655x; 1.1655x over previous
//
#include <hip/hip_runtime.h>
#include <hip/hip_bf16.h>
#include <hip/hip_cooperative_groups.h>
#include <cstddef>

typedef short bf16x8 __attribute__((ext_vector_type(8)));
typedef float f32x4 __attribute__((ext_vector_type(4)));

// Constants for this problem: V=4096, D=1024, H=1024, B=64, T=512

__device__ __forceinline__ short bf16rne(float f) {
  unsigned u = __builtin_bit_cast(unsigned, f);
  u += 0x7fffu + ((u >> 16) & 1u);
  return (short)(u >> 16);
}

// Inline tanh (no ocml call: a call forces caller-saved spills of wfrag).
__device__ __forceinline__ float fast_tanh(float x) {
  float e = __builtin_amdgcn_exp2f(x * 2.88539008177792681f);
  return 1.0f - 2.0f * __builtin_amdgcn_rcpf(e + 1.0f);
}

// Cache-bypassing flag load (sc0 sc1 -> reads the IF coherence point).
// waitcnt inside the asm: nothing can slip between issue and wait.
__device__ __forceinline__ unsigned load_if(const unsigned int* p) {
  unsigned v;
  asm volatile("global_load_dword %0, %1, off sc0 sc1\n\ts_waitcnt vmcnt(0)"
               : "=v"(v) : "v"(p) : "memory");
  return v;
}

// ---------------- K0a: elementwise f32 -> bf16 convert (x4 per thread) ----------------
__global__ void conv_f32_bf16_x4(const float* __restrict__ src, short* __restrict__ dst, int n4) {
  int i = blockIdx.x * blockDim.x + threadIdx.x;
  if (i >= n4) return;
  float4 v = ((const float4*)src)[i];
  unsigned long long o =
      (unsigned long long)(unsigned short)bf16rne(v.x) |
      ((unsigned long long)(unsigned short)bf16rne(v.y) << 16) |
      ((unsigned long long)(unsigned short)bf16rne(v.z) << 32) |
      ((unsigned long long)(unsigned short)bf16rne(v.w) << 48);
  ((unsigned long long*)dst)[i] = o;
}

// ---------------- K0b: tiled transpose + convert: dst[c][r] = bf16(src[r][c]) ----------------
__global__ void transpose_conv(const float* __restrict__ src, short* __restrict__ dst,
                               int R, int C) {
  __shared__ float tile[32][33];
  int tx = threadIdx.x, ty = threadIdx.y;
  int bx = blockIdx.x, by = blockIdx.y;
#pragma unroll
  for (int i = 0; i < 4; ++i)
    tile[ty + i * 8][tx] = src[(size_t)(by * 32 + ty + i * 8) * C + bx * 32 + tx];
  __syncthreads();
#pragma unroll
  for (int i = 0; i < 4; ++i)
    dst[(size_t)(bx * 32 + ty + i * 8) * R + by * 32 + tx] = bf16rne(tile[tx][ty + i * 8]);
}

// ---------------- K1/K3: 128x128 tile MFMA GEMM, BK=32, 4 waves (2x2 of 64x64) ----------------
template <bool GATHER, bool OUT_BF16>
__global__ __launch_bounds__(256) void gemm_bf16(
    const short* __restrict__ Abase, const int* __restrict__ gidx,
    const short* __restrict__ BT, const float* __restrict__ bias,
    void* __restrict__ Cout, int M, int N, int K) {
  __shared__ short As[128][40];
  __shared__ short Bs[128][40];
  const int tid = threadIdx.x;
  const int lane = tid & 63;
  const int wave = tid >> 6;
  const int mbase = blockIdx.x * 128;
  const int nbase = blockIdx.y * 128;
  const int wr = (wave >> 1) * 64;
  const int wc = (wave & 1) * 64;
  const int l15 = lane & 15;
  const int lk8 = (lane >> 4) * 8;
  const int r0 = tid >> 2;
  const int kc = (tid & 3) * 8;

  f32x4 acc[4][4] = {};

  for (int k0 = 0; k0 < K; k0 += 32) {
#pragma unroll
    for (int h = 0; h < 2; ++h) {
      int r = r0 + h * 64;
      size_t arow;
      if (GATHER) arow = (size_t)gidx[mbase + r];
      else        arow = (size_t)(mbase + r);
      *(bf16x8*)&As[r][kc] = *(const bf16x8*)(Abase + arow * (size_t)K + k0 + kc);
      *(bf16x8*)&Bs[r][kc] = *(const bf16x8*)(BT + (size_t)(nbase + r) * K + k0 + kc);
    }
    __syncthreads();
    bf16x8 af[4], bfr[4];
#pragma unroll
    for (int i = 0; i < 4; ++i) {
      af[i]  = *(const bf16x8*)&As[wr + i * 16 + l15][lk8];
      bfr[i] = *(const bf16x8*)&Bs[wc + i * 16 + l15][lk8];
    }
#pragma unroll
    for (int i = 0; i < 4; ++i)
#pragma unroll
      for (int j = 0; j < 4; ++j)
        acc[i][j] = __builtin_amdgcn_mfma_f32_16x16x32_bf16(af[i], bfr[j], acc[i][j], 0, 0, 0);
    __syncthreads();
  }

#pragma unroll
  for (int i = 0; i < 4; ++i)
#pragma unroll
    for (int j = 0; j < 4; ++j) {
      int col = nbase + wc + j * 16 + l15;
      float bv = bias ? bias[col] : 0.f;
#pragma unroll
      for (int r = 0; r < 4; ++r) {
        int row = mbase + wr + i * 16 + (lane >> 4) * 4 + r;
        float v = acc[i][j][r] + bv;
        if (OUT_BF16) ((short*)Cout)[(size_t)row * N + col] = bf16rne(v);
        else          ((float*)Cout)[(size_t)row * N + col] = v;
      }
    }
}

// ---------------- K2: recurrence — per-wave dataflow, NO barriers / NO atomics ----------------
// 64 blocks x 256 threads; rowgroup rg = bid>>4 owns batches [rg*16, rg*16+16);
// block m = bid&15 owns cols [m*64, +64); wave w owns cols [m*64+w*16, +16).
// Transposed MFMA (R9-proven): z^T = mfma(A=WrT-frag, B=h^T-frag); each lane
// stores one packed 8B = (batch rowbase+l15, 4 consecutive cols).
//
// Dataflow protocol per wave per step t:
//   store h_t slice (sc1 write-through) -> s_waitcnt vmcnt(0) (data at IF)
//   -> lane0 stores flag[t][rg][m*4+w]=1 (sc1)      [publish]
//   -> prefetch xp(t+2)
//   -> lanes 0..63 poll the 64 flags of step t (sc0 sc1), own flag skipped,
//      __ballot all-set -> release                    [subscribe]
// No s_barrier, no atomicAdd, no central counter: waves decouple, skew is
// absorbed instead of multiplied. Correct for ANY block placement (flags and
// data meet at the IF); hang-free (flags unconditional, dependence is the
// t-DAG); replay-safe (flags re-zeroed each launch).
__global__ __launch_bounds__(256, 1) void rnn_recur(
    const float* __restrict__ xp, const short* __restrict__ WrT,
    const float* __restrict__ h0, short* __restrict__ hs,
    unsigned int* __restrict__ flags) {
  const int tid = threadIdx.x;
  const int lane = tid & 63;
  const int wave = tid >> 6;
  const int bid = blockIdx.x;
  const int rg = bid >> 4;
  const int m = bid & 15;
  const int rowbase = rg * 16;
  const int colbase = m * 64 + wave * 16;
  const int l15 = lane & 15;
  const int lk8 = (lane >> 4) * 8;
  const int own_idx = m * 4 + wave;      // this wave's flag slot in [0,64)

  // A-operand: WrT rows = this wave's 16 output cols. Volatile: cannot remat.
  const int acol = colbase + l15;
  bf16x8 wfrag[32];
#pragma unroll
  for (int ks = 0; ks < 32; ++ks)
    wfrag[ks] = *(const volatile bf16x8*)(WrT + (size_t)acol * 1024 + ks * 32 + lk8);

  // Output mapping (transposed D): batch = rowbase+l15, 4 consecutive cols.
  const int ob = rowbase + l15;
  const int oc = colbase + (lane >> 4) * 4;

  // ---- t = 0: previous h is h0 (broadcast row); then publish flag[0] ----
  {
    f32x4 a0 = {}, a1 = {}, a2 = {}, a3 = {};
#pragma unroll
    for (int ks = 0; ks < 32; ks += 4) {
      bf16x8 a[4];
#pragma unroll
      for (int q = 0; q < 4; ++q) {
        const float* hp = h0 + (ks + q) * 32 + lk8;
#pragma unroll
        for (int jj = 0; jj < 8; ++jj) a[q][jj] = bf16rne(hp[jj]);
      }
      a0 = __builtin_amdgcn_mfma_f32_16x16x32_bf16(wfrag[ks + 0], a[0], a0, 0, 0, 0);
      a1 = __builtin_amdgcn_mfma_f32_16x16x32_bf16(wfrag[ks + 1], a[1], a1, 0, 0, 0);
      a2 = __builtin_amdgcn_mfma_f32_16x16x32_bf16(wfrag[ks + 2], a[2], a2, 0, 0, 0);
      a3 = __builtin_amdgcn_mfma_f32_16x16x32_bf16(wfrag[ks + 3], a[3], a3, 0, 0, 0);
    }
    f32x4 acc = (a0 + a1) + (a2 + a3);
    float4 x4 = *(const float4*)(xp + ((size_t)ob * 512 + 0) * 1024 + oc);
    unsigned long long p =
        (unsigned long long)(unsigned short)bf16rne(fast_tanh(acc[0] + x4.x)) |
        ((unsigned long long)(unsigned short)bf16rne(fast_tanh(acc[1] + x4.y)) << 16) |
        ((unsigned long long)(unsigned short)bf16rne(fast_tanh(acc[2] + x4.z)) << 32) |
        ((unsigned long long)(unsigned short)bf16rne(fast_tanh(acc[3] + x4.w)) << 48);
    __hip_atomic_store((unsigned long long*)(hs + ((size_t)ob * 512 + 0) * 1024 + oc),
                       p, __ATOMIC_RELAXED, __HIP_MEMORY_SCOPE_AGENT);
    asm volatile("s_waitcnt vmcnt(0)" ::: "memory");   // data at IF
    if (lane == 0)
      __hip_atomic_store(&flags[(size_t)(0 * 4 + rg) * 64 + own_idx], 1u,
                         __ATOMIC_RELAXED, __HIP_MEMORY_SCOPE_AGENT);
  }

  // prefetch xp for t = 1
  float4 xv = *(const float4*)(xp + ((size_t)ob * 512 + 1) * 1024 + oc);

  for (int t = 1; t < 512; ++t) {
    // prefetch xp for t+1 (static data) — flies while we poll
    const int tn = (t + 1 < 512) ? (t + 1) : 511;
    float4 xn = *(const float4*)(xp + ((size_t)ob * 512 + tn) * 1024 + oc);

    // subscribe: poll the 64 producer flags of step t-1 (lane ll -> flag ll);
    // own flag substituted true (skips same-address load-after-store hazard)
    {
      const unsigned int* fb = flags + (size_t)((t - 1) * 4 + rg) * 64;
      for (;;) {
        unsigned fv = load_if(fb + lane);
        bool ok = (fv != 0u) || (lane == own_idx);
        if (__ballot(ok) == ~0ull) break;
        __builtin_amdgcn_s_sleep(1);
      }
    }
    asm volatile("" ::: "memory");        // no static hoist of h loads above
    __builtin_amdgcn_sched_barrier(0);    // rule 18: pin ordering

    // B = h_{t-1}^T (batch ob): addresses fresh this step -> L1 miss -> local
    // L2 write-through copy or IF. 4 independent accumulator chains.
    f32x4 a0 = {}, a1 = {}, a2 = {}, a3 = {};
    const short* hrow = hs + ((size_t)ob * 512 + (t - 1)) * 1024 + lk8;
#pragma unroll
    for (int ks = 0; ks < 32; ks += 4) {
      bf16x8 a[4];
#pragma unroll
      for (int q = 0; q < 4; ++q)
        a[q] = *(const bf16x8*)(hrow + (ks + q) * 32);
      a0 = __builtin_amdgcn_mfma_f32_16x16x32_bf16(wfrag[ks + 0], a[0], a0, 0, 0, 0);
      a1 = __builtin_amdgcn_mfma_f32_16x16x32_bf16(wfrag[ks + 1], a[1], a1, 0, 0, 0);
      a2 = __builtin_amdgcn_mfma_f32_16x16x32_bf16(wfrag[ks + 2], a[2], a2, 0, 0, 0);
      a3 = __builtin_amdgcn_mfma_f32_16x16x32_bf16(wfrag[ks + 3], a[3], a3, 0, 0, 0);
    }
    f32x4 acc = (a0 + a1) + (a2 + a3);

    // store h_t slice (sc1), drain to IF, publish flag[t]
    unsigned long long p =
        (unsigned long long)(unsigned short)bf16rne(fast_tanh(acc[0] + xv.x)) |
        ((unsigned long long)(unsigned short)bf16rne(fast_tanh(acc[1] + xv.y)) << 16) |
        ((unsigned long long)(unsigned short)bf16rne(fast_tanh(acc[2] + xv.z)) << 32) |
        ((unsigned long long)(unsigned short)bf16rne(fast_tanh(acc[3] + xv.w)) << 48);
    __hip_atomic_store((unsigned long long*)(hs + ((size_t)ob * 512 + t) * 1024 + oc),
                       p, __ATOMIC_RELAXED, __HIP_MEMORY_SCOPE_AGENT);
    asm volatile("s_waitcnt vmcnt(0)" ::: "memory");   // data at IF
    if (lane == 0)
      __hip_atomic_store(&flags[(size_t)(t * 4 + rg) * 64 + own_idx], 1u,
                         __ATOMIC_RELAXED, __HIP_MEMORY_SCOPE_AGENT);
    xv = xn;
  }
}

// ---------------- launch ----------------
extern "C" void kernel_launch(void* const* d_in, const int* in_sizes, int n_in,
                              void* d_out, int out_size, void* d_ws, size_t ws_size,
                              hipStream_t stream) {
  const int*   input = (const int*)d_in[0];    // [B][T] = [64][512]
  const float* embed = (const float*)d_in[1];  // [V][D] = [4096][1024]
  const float* Wc    = (const float*)d_in[2];  // [D+H][H] = [2048][1024]
  const float* bc    = (const float*)d_in[3];  // [H]
  const float* h0    = (const float*)d_in[4];  // [1][H]
  const float* Wh    = (const float*)d_in[5];  // [H][V] = [1024][4096]
  const float* bh    = (const float*)d_in[6];  // [V]

  char* ws = (char*)d_ws;
  float* xp   = (float*)(ws + 0);            // 32768*1024 f32  = 134,217,728 B
  short* hs   = (short*)(ws + 134217728);    // 32768*1024 bf16 =  67,108,864 B
  short* embB = (short*)(ws + 201326592);    // 4096*1024 bf16  =   8,388,608 B
  short* WxT  = (short*)(ws + 209715200);    // 1024*1024 bf16  =   2,097,152 B
  short* WrT  = (short*)(ws + 211812352);    // 1024*1024 bf16  =   2,097,152 B
  short* WhT  = (short*)(ws + 213909504);    // 4096*1024 bf16  =   8,388,608 B
  unsigned int* flags = (unsigned int*)(ws + 222298112);  // 512 KB flag array

  // flags must be zero at every launch (t-indexed, written once per step)
  hipMemsetAsync(flags, 0, 2048 * 64 * 4, stream);

  // K0: converts + transposes
  conv_f32_bf16_x4<<<4096, 256, 0, stream>>>(embed, embB, 1048576);
  transpose_conv<<<dim3(32, 32),  dim3(32, 8), 0, stream>>>(Wc,                WxT, 1024, 1024);
  transpose_conv<<<dim3(32, 32),  dim3(32, 8), 0, stream>>>(Wc + 1024 * 1024,  WrT, 1024, 1024);
  transpose_conv<<<dim3(128, 32), dim3(32, 8), 0, stream>>>(Wh,                WhT, 1024, 4096);

  // K1: xp = embed[input] @ Wx + bc   (f32 out)
  gemm_bf16<true, false><<<dim3(256, 8), 256, 0, stream>>>(
      embB, input, WxT, bc, (void*)xp, 32768, 1024, 1024);

  // K2: recurrence (cooperative launch for guaranteed co-residency)
  {
    const float* xp_c = xp;
    const short* WrT_c = WrT;
    const float* h0_c = h0;
    short* hs_c = hs;
    unsigned int* flags_c = flags;
    void* args[] = {(void*)&xp_c, (void*)&WrT_c, (void*)&h0_c, (void*)&hs_c, (void*)&flags_c};
    hipLaunchCooperativeKernel((const void*)rnn_recur, dim3(64), dim3(256), args, 0, stream);
  }

  // K3: out = hs @ Wh + bh  (f32 out)
  gemm_bf16<false, false><<<dim3(256, 32), 256, 0, stream>>>(
      hs, nullptr, WhT, bh, d_out, 32768, 4096, 1024);
}